// Round 7
// baseline (1849.310 us; speedup 1.0000x reference)
//
#include <hip/hip_runtime.h>
#include <stdint.h>

#define BATCH 512
#define TMAX  1024
#define NC    1098
#define H     64
#define CH    8    // layer-1 xW chunk: one block-barrier per CH steps
#define G16   16   // layer-0: sequences per block (MFMA N-batch)

typedef __attribute__((ext_vector_type(2))) float    v2;
typedef __attribute__((ext_vector_type(2))) _Float16 h2;
typedef __attribute__((ext_vector_type(8))) _Float16 f16x8;
typedef __attribute__((ext_vector_type(4))) float    f32x4;

__device__ __forceinline__ v2 mkv2(float a, float b) { v2 r; r.x = a; r.y = b; return r; }
__device__ __forceinline__ float sigmoidf_(float x) { return 1.0f / (1.0f + __expf(-x)); }
__device__ __forceinline__ float tanhf_(float x) { return 1.0f - 2.0f / (__expf(2.0f * x) + 1.0f); }
__device__ __forceinline__ h2 u2h(uint32_t u) { union { uint32_t u; h2 h; } c; c.u = u; return c.h; }

__device__ __forceinline__ float fdot2_(h2 w, h2 x, float acc) {
    return __builtin_amdgcn_fdot2(w, x, acc, false);
}

// ============ Layer 0: MFMA-batched recurrence, 16 seqs/block ==============
// R6 post-mortem: the VALU recurrence is latency/issue-walled at ~1400
// cyc/step regardless of structure (R0 1480, R3 1275, R6 1410). Fix: batch
// 16 same-direction sequences per block; per step ONE matrix op computes all
// gates: D[16 seq x 256 gate] = H^T[16x64] . [Whh^T ; Wih^T] (K=64+4, x-term
// folded into K-tile 2, bias preloaded into the MFMA C operand). 4 waves x
// 4 gate-tiles (wave w owns h-idx 16w..16w+15); B columns permuted so lane
// (q,m16) gets all 4 gates of (seq=4q+r, h-idx=16w+m16) -> lane-local cell
// update. h exchanged via 4.6 KB dbuf LDS H; ONE barrier/step.
// Fragment maps: C/D col=lane&15,row=(lane>>4)*4+reg (HW-verified m89);
// A row=lane&15,k=8*(lane>>4)+j; B col=lane&15,k=8*(lane>>4)+j.
__global__ __launch_bounds__(256) void lstm_l0(
    const float* __restrict__ x, const int* __restrict__ lengths,
    const float* __restrict__ Wih_f, const float* __restrict__ Whh_f,
    const float* __restrict__ bih_f, const float* __restrict__ bhh_f,
    const float* __restrict__ Wih_b, const float* __restrict__ Whh_b,
    const float* __restrict__ bih_b, const float* __restrict__ bhh_b,
    _Float16* __restrict__ h0 /* [B, T, 128] f16 */)
{
    const int bid = blockIdx.x;
    const int dir = bid >> 5;             // 0..31 fwd, 32..63 bwd
    const int g   = bid & 31;             // seq group: seqs 16g..16g+15
    const int t   = threadIdx.x;
    const int w   = t >> 6;               // wave w owns h-idx 16w..16w+15
    const int l   = t & 63;
    const int q   = l >> 4;               // lane quarter
    const int m16 = l & 15;

    const float* Wih = dir ? Wih_b : Wih_f;
    const float* Whh = dir ? Whh_b : Whh_f;
    const float* bih = dir ? bih_b : bih_f;
    const float* bhh = dir ? bhh_b : bhh_f;

    // ---- static B fragments: tile tt = gate tt, tile col m16 -> gate row
    // tt*64 + 16w + m16. B[k][n] = Whh[n-row][k] (K-tiles 0,1), Wih (tile 2).
    f16x8 bf[4][2];
    f16x8 bx[4];
    float bb[4];
    #pragma unroll
    for (int tt = 0; tt < 4; tt++) {
        const int row = tt*64 + 16*w + m16;
        #pragma unroll
        for (int kk = 0; kk < 2; kk++) {
            const float4* p4 = (const float4*)(Whh + (size_t)row * H + kk*32 + 8*q);
            float4 v0 = p4[0], v1 = p4[1];
            f16x8 f;
            f[0]=(_Float16)v0.x; f[1]=(_Float16)v0.y; f[2]=(_Float16)v0.z; f[3]=(_Float16)v0.w;
            f[4]=(_Float16)v1.x; f[5]=(_Float16)v1.y; f[6]=(_Float16)v1.z; f[7]=(_Float16)v1.w;
            bf[tt][kk] = f;
        }
        f16x8 fx;
        #pragma unroll
        for (int j = 0; j < 8; j++) fx[j] = (_Float16)0.0f;
        if (q == 0) {                     // real K only 0..3 of x K-tile
            const float4 xv = *(const float4*)(Wih + (size_t)row * 4);
            fx[0]=(_Float16)xv.x; fx[1]=(_Float16)xv.y;
            fx[2]=(_Float16)xv.z; fx[3]=(_Float16)xv.w;
        }
        bx[tt] = fx;
        bb[tt] = bih[row] + bhh[row];
    }

    // per-lane sequence metadata
    const int nsteps = lengths[G16 * g];  // sorted desc -> group max
    const int LrA = lengths[G16*g + m16]; // A-row seq (x fragment)
    int Ls[4];
    #pragma unroll
    for (int r = 0; r < 4; r++) Ls[r] = lengths[G16*g + 4*q + r];

    // H double buffer: [parity][seq m][h-idx k], row stride 72 f16 (16B-align)
    __shared__ _Float16 Hb[2][16][72];
    for (int i = t; i < 2*16*72; i += 256) (&Hb[0][0][0])[i] = (_Float16)0.0f;
    __syncthreads();

    float c4[4] = {0.f, 0.f, 0.f, 0.f};
    const float* xrowA = x + (size_t)(G16*g + m16) * TMAX * 4;

    float4 xcur = make_float4(0.f, 0.f, 0.f, 0.f);
    if (q == 0) {
        const int tt0 = dir ? (LrA - 1) : 0;
        xcur = *(const float4*)(xrowA + (size_t)tt0 * 4);
    }

    int p = 0;
    for (int s = 0; s < nsteps; s++) {
        // A fragments: h part from LDS, x part from prefetched regs
        f16x8 a0 = *(const f16x8*)&Hb[p][m16][8*q];
        f16x8 a1 = *(const f16x8*)&Hb[p][m16][32 + 8*q];
        f16x8 ax;
        #pragma unroll
        for (int j = 0; j < 8; j++) ax[j] = (_Float16)0.0f;
        if (q == 0) {
            ax[0]=(_Float16)xcur.x; ax[1]=(_Float16)xcur.y;
            ax[2]=(_Float16)xcur.z; ax[3]=(_Float16)xcur.w;
        }
        // prefetch x for s+1 (off critical path; clamped for finished seqs)
        float4 xnxt = make_float4(0.f, 0.f, 0.f, 0.f);
        if (q == 0 && s + 1 < nsteps) {
            int tn = dir ? (LrA - 2 - s) : (s + 1);
            tn = tn < 0 ? 0 : (tn >= LrA ? LrA - 1 : tn);
            xnxt = *(const float4*)(xrowA + (size_t)tn * 4);
        }

        f32x4 acc0, acc1, acc2, acc3;     // static names (rule #20)
        acc0[0]=bb[0]; acc0[1]=bb[0]; acc0[2]=bb[0]; acc0[3]=bb[0];
        acc1[0]=bb[1]; acc1[1]=bb[1]; acc1[2]=bb[1]; acc1[3]=bb[1];
        acc2[0]=bb[2]; acc2[1]=bb[2]; acc2[2]=bb[2]; acc2[3]=bb[2];
        acc3[0]=bb[3]; acc3[1]=bb[3]; acc3[2]=bb[3]; acc3[3]=bb[3];
        acc0 = __builtin_amdgcn_mfma_f32_16x16x32_f16(a0, bf[0][0], acc0, 0,0,0);
        acc1 = __builtin_amdgcn_mfma_f32_16x16x32_f16(a0, bf[1][0], acc1, 0,0,0);
        acc2 = __builtin_amdgcn_mfma_f32_16x16x32_f16(a0, bf[2][0], acc2, 0,0,0);
        acc3 = __builtin_amdgcn_mfma_f32_16x16x32_f16(a0, bf[3][0], acc3, 0,0,0);
        acc0 = __builtin_amdgcn_mfma_f32_16x16x32_f16(a1, bf[0][1], acc0, 0,0,0);
        acc1 = __builtin_amdgcn_mfma_f32_16x16x32_f16(a1, bf[1][1], acc1, 0,0,0);
        acc2 = __builtin_amdgcn_mfma_f32_16x16x32_f16(a1, bf[2][1], acc2, 0,0,0);
        acc3 = __builtin_amdgcn_mfma_f32_16x16x32_f16(a1, bf[3][1], acc3, 0,0,0);
        acc0 = __builtin_amdgcn_mfma_f32_16x16x32_f16(ax, bx[0], acc0, 0,0,0);
        acc1 = __builtin_amdgcn_mfma_f32_16x16x32_f16(ax, bx[1], acc1, 0,0,0);
        acc2 = __builtin_amdgcn_mfma_f32_16x16x32_f16(ax, bx[2], acc2, 0,0,0);
        acc3 = __builtin_amdgcn_mfma_f32_16x16x32_f16(ax, bx[3], acc3, 0,0,0);

        // cell update: lane owns (seq = 4q+r, h-idx = 16w+m16), gates i,f,g,o
        #pragma unroll
        for (int r = 0; r < 4; r++) {
            const float gi = sigmoidf_(acc0[r]);
            const float gf = sigmoidf_(acc1[r]);
            const float gg = tanhf_(acc2[r]);
            const float go = sigmoidf_(acc3[r]);
            c4[r] = fmaf(gf, c4[r], gi * gg);
            const float hv = go * tanhf_(c4[r]);
            const _Float16 hf = (_Float16)hv;
            Hb[p ^ 1][4*q + r][16*w + m16] = hf;
            if (s < Ls[r]) {
                const int seq = G16*g + 4*q + r;
                const int trt = dir ? (Ls[r] - 1 - s) : s;
                h0[((size_t)seq * TMAX + trt) * 128 + dir*64 + 16*w + m16] = hf;
            }
        }
        xcur = xnxt;
        __syncthreads();                  // ONE barrier per step
        p ^= 1;
    }
}

// ====== Layer 1: 1 consumer + 2 producer waves per seq, barrier per CH=8 ====
// (VERBATIM from validated R6: 609 us, absmax 9.8e-4.)
__global__ __launch_bounds__(384) void lstm_l1(
    const _Float16* __restrict__ h0, const int* __restrict__ lengths,
    const float* __restrict__ Wih,  const float* __restrict__ Whh,
    const float* __restrict__ bih,  const float* __restrict__ bhh,
    const float* __restrict__ WihB, const float* __restrict__ bihB,
    const float* __restrict__ bhhB,
    const float* __restrict__ Wout, const float* __restrict__ bout,
    float* __restrict__ out)
{
    const int bk = blockIdx.x;
    const int t = threadIdx.x;
    const int grp = (t >= 192) ? 1 : 0;
    const int tl = t - 192 * grp;         // 0..191 within group
    const int wl = tl >> 6;               // 0 consumer, 1..2 producers
    const int l = tl & 63;
    const int seq = grp ? (BATCH - 1 - bk) : bk;
    const int L = lengths[seq];
    const int nch = (L + CH - 1) / CH;
    const int nchMax = (lengths[bk] + CH - 1) / CH;  // L[bk] >= L[511-bk]

    __shared__ __align__(16) float    xw[2][2][CH][256];   // 32 KB xW dbuf
    __shared__ __align__(16) _Float16 hst[2][2][CH][128];  // 8 KB h0 dbuf
    __shared__ __align__(16) _Float16 hln[2][H];           // consumer h lines
    __shared__ __align__(16) float    ybuf[2][2*H];
    __shared__ __align__(16) float    gb[2][192];
    __shared__ __align__(16) float    h0r[2][128];

    const _Float16* hseq = h0 + (size_t)seq * TMAX * 128;

    h2 wsh[128];
    float bb[4] = {0.f, 0.f, 0.f, 0.f};
    int rA = 0, rB = 0;
    if (wl == 0) {
        #pragma unroll
        for (int g = 0; g < 4; g++) {
            const float4* pw = (const float4*)(Whh + (size_t)(64*g + l) * H);
            #pragma unroll
            for (int k = 0; k < 16; k++) {
                float4 a = pw[k];
                h2 lo; lo.x = (_Float16)a.x; lo.y = (_Float16)a.y;
                h2 hi; hi.x = (_Float16)a.z; hi.y = (_Float16)a.w;
                wsh[g*32 + 2*k]   = lo;
                wsh[g*32 + 2*k+1] = hi;
            }
            bb[g] = bih[64*g + l] + bhh[64*g + l];
        }
        hln[grp][l] = (_Float16)0.0f;     // own-wave line, no barrier needed
    } else {
        const int pw = wl - 1;
        rA = pw * 128 + l; rB = pw * 128 + 64 + l;
        const float4* pa = (const float4*)(Wih + (size_t)rA * 128);
        const float4* pb = (const float4*)(Wih + (size_t)rB * 128);
        #pragma unroll
        for (int k = 0; k < 32; k++) {
            float4 a = pa[k], b2 = pb[k];
            h2 alo; alo.x = (_Float16)a.x;  alo.y = (_Float16)a.y;
            h2 ahi; ahi.x = (_Float16)a.z;  ahi.y = (_Float16)a.w;
            h2 blo; blo.x = (_Float16)b2.x; blo.y = (_Float16)b2.y;
            h2 bhi; bhi.x = (_Float16)b2.z; bhi.y = (_Float16)b2.w;
            wsh[2*k]        = alo;
            wsh[2*k + 1]    = ahi;
            wsh[64 + 2*k]   = blo;
            wsh[64 + 2*k+1] = bhi;
        }
    }

    uint4 st0;
    auto stage_load = [&](int ck) {
        const uint4* gp = (const uint4*)(hseq + (size_t)ck * CH * 128);
        st0 = gp[(wl - 1) * 64 + l];
    };
    auto stage_store = [&](int ck) {
        uint4* dp = (uint4*)&hst[grp][ck & 1][0][0];
        dp[(wl - 1) * 64 + l] = st0;
    };
    auto produce = [&](int ck) {
        const int par = ck & 1;
        for (int r = 0; r < CH; r++) {
            const uint4* rp = (const uint4*)&hst[grp][par][r][0];
            float aA = 0.f, aB = 0.f;
            #pragma unroll
            for (int q = 0; q < 16; q++) {
                uint4 u = rp[q];
                h2 p0 = u2h(u.x), p1 = u2h(u.y), p2 = u2h(u.z), p3 = u2h(u.w);
                aA = fdot2_(wsh[4*q+0], p0, aA);
                aA = fdot2_(wsh[4*q+1], p1, aA);
                aA = fdot2_(wsh[4*q+2], p2, aA);
                aA = fdot2_(wsh[4*q+3], p3, aA);
                aB = fdot2_(wsh[64+4*q+0], p0, aB);
                aB = fdot2_(wsh[64+4*q+1], p1, aB);
                aB = fdot2_(wsh[64+4*q+2], p2, aB);
                aB = fdot2_(wsh[64+4*q+3], p3, aB);
            }
            xw[grp][par][r][rA] = aA;
            xw[grp][par][r][rB] = aB;
        }
    };

    float c = 0.f, h = 0.f;

    if (wl >= 1) { stage_load(0); stage_store(0); if (nch > 1) stage_load(1); }
    __syncthreads();
    if (wl >= 1) { produce(0); if (nch > 1) stage_store(1); }
    __syncthreads();

    for (int cc = 0; cc < nchMax; cc++) {
        if (wl == 0) {
            const int sbeg = cc * CH;
            const int send = (sbeg + CH < L) ? (sbeg + CH) : L;
            const int par = cc & 1;
            for (int s = sbeg; s < send; s++) {
                const int r = s - sbeg;
                float p[4];
                #pragma unroll
                for (int g = 0; g < 4; g++)
                    p[g] = xw[grp][par][r][g*64 + l] + bb[g];
                float acA[4] = {0.f,0.f,0.f,0.f}, acB[4] = {0.f,0.f,0.f,0.f};
                const uint4* h4 = (const uint4*)&hln[grp][0];
                #pragma unroll
                for (int q = 0; q < 8; q++) {
                    uint4 u = h4[q];
                    h2 p0 = u2h(u.x), p1 = u2h(u.y), p2 = u2h(u.z), p3 = u2h(u.w);
                    #pragma unroll
                    for (int g = 0; g < 4; g++) {
                        acA[g] = fdot2_(wsh[g*32+4*q+0], p0, acA[g]);
                        acA[g] = fdot2_(wsh[g*32+4*q+1], p1, acA[g]);
                        acB[g] = fdot2_(wsh[g*32+4*q+2], p2, acB[g]);
                        acB[g] = fdot2_(wsh[g*32+4*q+3], p3, acB[g]);
                    }
                }
                #pragma unroll
                for (int g = 0; g < 4; g++) p[g] += acA[g] + acB[g];
                const float gi = sigmoidf_(p[0]);
                const float gf = sigmoidf_(p[1]);
                const float gg = tanhf_(p[2]);
                const float go = sigmoidf_(p[3]);
                c = fmaf(gf, c, gi * gg);
                h = go * tanhf_(c);
                hln[grp][l] = (_Float16)h;    // own-wave, no barrier
            }
        } else {
            if (cc + 2 < nch) stage_load(cc + 2);
            if (cc + 1 < nch) produce(cc + 1);
            if (cc + 2 < nch) stage_store(cc + 2);
        }
        __syncthreads();                  // ONE barrier per CH steps
    }

    // ---- epilogue: y = [h1f_last, h1b_first]; logits = y @ Wout^T + bout ---
    if (wl == 0) ybuf[grp][l] = h;
    if (tl < 128) h0r[grp][tl] = (float)hseq[(size_t)(L - 1) * 128 + tl];
    __syncthreads();
    {
        const int row = (tl < 64) ? tl : (tl + 64);
        const float4* wr = (const float4*)(WihB + (size_t)row * 128);
        const float4* xr = (const float4*)&h0r[grp][0];
        v2 a0 = mkv2(bihB[row] + bhhB[row], 0.f), a1 = mkv2(0.f, 0.f);
        #pragma unroll
        for (int k = 0; k < 32; k++) {
            float4 wv = wr[k], xv = xr[k];
            a0 += mkv2(wv.x, wv.y) * mkv2(xv.x, xv.y);
            a1 += mkv2(wv.z, wv.w) * mkv2(xv.z, xv.w);
        }
        const float a = (a0.x + a0.y) + (a1.x + a1.y);
        gb[grp][tl] = (tl >= 64 && tl < 128) ? tanhf_(a) : sigmoidf_(a);
    }
    __syncthreads();
    if (tl < 64) {
        // gb holds ACTIVATED gates: sigma(i), tanh(g), sigma(o) — combine raw
        const float hb = gb[grp][128 + tl] * tanhf_(gb[grp][tl] * gb[grp][64 + tl]);
        ybuf[grp][H + tl] = hb;
    }
    __syncthreads();
    const float4* yv = (const float4*)&ybuf[grp][0];
    for (int o = tl; o < NC; o += 192) {
        const float4* wr = (const float4*)(Wout + (size_t)o * 128);
        v2 a0 = mkv2(bout[o], 0.f), a1 = mkv2(0.f, 0.f);
        #pragma unroll
        for (int k = 0; k < 32; k++) {
            float4 wv = wr[k], yy = yv[k];
            a0 += mkv2(wv.x, wv.y) * mkv2(yy.x, yy.y);
            a1 += mkv2(wv.z, wv.w) * mkv2(yy.z, yy.w);
        }
        out[(size_t)seq * NC + o] = (a0.x + a0.y) + (a1.x + a1.y);
    }
}

extern "C" void kernel_launch(void* const* d_in, const int* in_sizes, int n_in,
                              void* d_out, int out_size, void* d_ws, size_t ws_size,
                              hipStream_t stream) {
    const float* x        = (const float*)d_in[0];
    const int*   lengths  = (const int*)  d_in[1];
    const float* Wih_l0f  = (const float*)d_in[2];
    const float* Whh_l0f  = (const float*)d_in[3];
    const float* bih_l0f  = (const float*)d_in[4];
    const float* bhh_l0f  = (const float*)d_in[5];
    const float* Wih_l0b  = (const float*)d_in[6];
    const float* Whh_l0b  = (const float*)d_in[7];
    const float* bih_l0b  = (const float*)d_in[8];
    const float* bhh_l0b  = (const float*)d_in[9];
    const float* Wih_l1f  = (const float*)d_in[10];
    const float* Whh_l1f  = (const float*)d_in[11];
    const float* bih_l1f  = (const float*)d_in[12];
    const float* bhh_l1f  = (const float*)d_in[13];
    const float* Wih_l1b  = (const float*)d_in[14];
    // d_in[15] = Whh_l1b: unused (backward dir only needs its first step, h=0)
    const float* bih_l1b  = (const float*)d_in[16];
    const float* bhh_l1b  = (const float*)d_in[17];
    const float* Wout     = (const float*)d_in[18];
    const float* bout     = (const float*)d_in[19];
    float* out = (float*)d_out;

    // ws: h0 f16 [B, T, 128] = 128 MiB
    _Float16* h0 = (_Float16*)d_ws;

    lstm_l0<<<dim3(64), 256, 0, stream>>>(
        x, lengths,
        Wih_l0f, Whh_l0f, bih_l0f, bhh_l0f,
        Wih_l0b, Whh_l0b, bih_l0b, bhh_l0b, h0);

    lstm_l1<<<dim3(BATCH / 2), 384, 0, stream>>>(
        h0, lengths,
        Wih_l1f, Whh_l1f, bih_l1f, bhh_l1f,
        Wih_l1b, bih_l1b, bhh_l1b, Wout, bout, out);
}

// Round 8
// 1247.557 us; speedup vs baseline: 1.4823x; 1.4823x over previous
//
#include <hip/hip_runtime.h>
#include <stdint.h>

#define BATCH 512
#define TMAX  1024
#define NC    1098
#define H     64
#define CH    8    // layer-1 xW chunk: one block-barrier per CH steps

typedef __attribute__((ext_vector_type(2))) float    v2;
typedef __attribute__((ext_vector_type(2))) _Float16 h2;

__device__ __forceinline__ v2 mkv2(float a, float b) { v2 r; r.x = a; r.y = b; return r; }
__device__ __forceinline__ float sigmoidf_(float x) { return 1.0f / (1.0f + __expf(-x)); }
__device__ __forceinline__ float tanhf_(float x) { return 1.0f - 2.0f / (__expf(2.0f * x) + 1.0f); }
__device__ __forceinline__ h2 u2h(uint32_t u) { union { uint32_t u; h2 h; } c; c.u = u; return c.h; }

__device__ __forceinline__ float fdot2_(h2 w, h2 x, float acc) {
    return __builtin_amdgcn_fdot2(w, x, acc, false);
}

// ============ Layer 0: paired sequences, 4 waves/block, zero step barriers ==
// Structure = R6 (validated, 602us). R8 change: the dot2 accumulators are
// widened from 8 chains with BACK-TO-BACK same-chain issue to 16 chains in
// round-robin (same-chain ops 16 instructions apart). R7 post-mortem: the
// ~1400cyc/step wall was invariant across R0/R3/R6 structures -> instruction
// -level stall; consecutive dependent fdot2s eat the full result latency.
__global__ __launch_bounds__(256) void lstm_l0(
    const float* __restrict__ x, const int* __restrict__ lengths,
    const float* __restrict__ Wih_f, const float* __restrict__ Whh_f,
    const float* __restrict__ bih_f, const float* __restrict__ bhh_f,
    const float* __restrict__ Wih_b, const float* __restrict__ Whh_b,
    const float* __restrict__ bih_b, const float* __restrict__ bhh_b,
    _Float16* __restrict__ h0 /* [B, T, 128] f16 */)
{
    const int bk = blockIdx.x;
    const int t = threadIdx.x;
    const int j = t & 63, w = t >> 6;     // w in 0..3
    const int seq = (w < 2) ? bk : (BATCH - 1 - bk);
    const int dir = w & 1;
    const int xb  = w >> 1;               // which xbuf
    const int L = lengths[seq];

    const float* Wih = dir ? Wih_b : Wih_f;
    const float* Whh = dir ? Whh_b : Whh_f;
    const float* bih = dir ? bih_b : bih_f;
    const float* bhh = dir ? bhh_b : bhh_f;

    h2 wh[4][32];                         // 256 f16 = 128 VGPRs
    #pragma unroll
    for (int g = 0; g < 4; g++) {
        const float4* pw = (const float4*)(Whh + (size_t)(64*g + j) * H);
        #pragma unroll
        for (int k = 0; k < 16; k++) {
            float4 a = pw[k];
            h2 lo; lo.x = (_Float16)a.x; lo.y = (_Float16)a.y;
            h2 hi; hi.x = (_Float16)a.z; hi.y = (_Float16)a.w;
            wh[g][2*k]   = lo;
            wh[g][2*k+1] = hi;
        }
    }
    float4 wx[4]; float bb[4];
    #pragma unroll
    for (int g = 0; g < 4; g++) {
        wx[g] = ((const float4*)Wih)[64*g + j];
        bb[g] = bih[64*g + j] + bhh[64*g + j];
    }

    __shared__ __align__(16) float4    xbuf[2][TMAX];  // 32 KB: x of both seqs
    __shared__ __align__(16) _Float16  hln[4][H];      // per-wave h line (f16)
    {
        const int sA = bk, sB = BATCH - 1 - bk;
        const int LA = lengths[sA], LB = lengths[sB];
        const float4* xA = (const float4*)x + (size_t)sA * TMAX;
        const float4* xB = (const float4*)x + (size_t)sB * TMAX;
        for (int i = t; i < LA; i += 256) xbuf[0][i] = xA[i];
        for (int i = t; i < LB; i += 256) xbuf[1][i] = xB[i];
    }
    hln[w][j] = (_Float16)0.0f;
    float c = 0.0f;
    __syncthreads();                      // the ONLY barrier in this kernel

    _Float16* outp = h0 + (size_t)seq * TMAX * 128 + dir * H + j;

    for (int s = 0; s < L; s++) {
        const int tt = dir ? (L - 1 - s) : s;
        const float4 xt = xbuf[xb][tt];   // uniform -> LDS broadcast
        float p[4];
        #pragma unroll
        for (int g = 0; g < 4; g++)
            p[g] = fmaf(wx[g].w, xt.w, fmaf(wx[g].z, xt.z,
                   fmaf(wx[g].y, xt.y, fmaf(wx[g].x, xt.x, bb[g]))));
        // 16 independent dot2 chains, round-robin issue (R8 change)
        float ac0[4] = {0.f,0.f,0.f,0.f}, ac1[4] = {0.f,0.f,0.f,0.f};
        float ac2[4] = {0.f,0.f,0.f,0.f}, ac3[4] = {0.f,0.f,0.f,0.f};
        const uint4* h4 = (const uint4*)&hln[w][0];
        #pragma unroll
        for (int q = 0; q < 8; q++) {
            uint4 u = h4[q];              // broadcast b128: 8 f16 of h
            h2 p0 = u2h(u.x), p1 = u2h(u.y), p2 = u2h(u.z), p3 = u2h(u.w);
            #pragma unroll
            for (int g = 0; g < 4; g++) ac0[g] = fdot2_(wh[g][4*q+0], p0, ac0[g]);
            #pragma unroll
            for (int g = 0; g < 4; g++) ac1[g] = fdot2_(wh[g][4*q+1], p1, ac1[g]);
            #pragma unroll
            for (int g = 0; g < 4; g++) ac2[g] = fdot2_(wh[g][4*q+2], p2, ac2[g]);
            #pragma unroll
            for (int g = 0; g < 4; g++) ac3[g] = fdot2_(wh[g][4*q+3], p3, ac3[g]);
        }
        #pragma unroll
        for (int g = 0; g < 4; g++)
            p[g] += (ac0[g] + ac1[g]) + (ac2[g] + ac3[g]);
        const float gi = sigmoidf_(p[0]);
        const float gf = sigmoidf_(p[1]);
        const float gg = tanhf_(p[2]);
        const float go = sigmoidf_(p[3]);
        c = fmaf(gf, c, gi * gg);
        const float h = go * tanhf_(c);
        hln[w][j] = (_Float16)h;          // same-wave ordering, no barrier
        outp[(size_t)tt * 128] = (_Float16)h;
    }
}

// ====== Layer 1: 1 consumer + 2 producer waves per seq, barrier per CH=8 ====
// Structure = R6 (validated, 609us). R8 change: consumer widened to 16 dot2
// chains (round-robin); producer's 4-long SERIAL runs on aA/aB split into
// 8 chains (aA0..3, aB0..3) issued round-robin.
__global__ __launch_bounds__(384) void lstm_l1(
    const _Float16* __restrict__ h0, const int* __restrict__ lengths,
    const float* __restrict__ Wih,  const float* __restrict__ Whh,
    const float* __restrict__ bih,  const float* __restrict__ bhh,
    const float* __restrict__ WihB, const float* __restrict__ bihB,
    const float* __restrict__ bhhB,
    const float* __restrict__ Wout, const float* __restrict__ bout,
    float* __restrict__ out)
{
    const int bk = blockIdx.x;
    const int t = threadIdx.x;
    const int grp = (t >= 192) ? 1 : 0;
    const int tl = t - 192 * grp;         // 0..191 within group
    const int wl = tl >> 6;               // 0 consumer, 1..2 producers
    const int l = tl & 63;
    const int seq = grp ? (BATCH - 1 - bk) : bk;
    const int L = lengths[seq];
    const int nch = (L + CH - 1) / CH;
    const int nchMax = (lengths[bk] + CH - 1) / CH;  // L[bk] >= L[511-bk]

    __shared__ __align__(16) float    xw[2][2][CH][256];   // 32 KB xW dbuf
    __shared__ __align__(16) _Float16 hst[2][2][CH][128];  // 8 KB h0 dbuf
    __shared__ __align__(16) _Float16 hln[2][H];           // consumer h lines
    __shared__ __align__(16) float    ybuf[2][2*H];
    __shared__ __align__(16) float    gb[2][192];
    __shared__ __align__(16) float    h0r[2][128];

    const _Float16* hseq = h0 + (size_t)seq * TMAX * 128;

    h2 wsh[128];
    float bb[4] = {0.f, 0.f, 0.f, 0.f};
    int rA = 0, rB = 0;
    if (wl == 0) {
        #pragma unroll
        for (int g = 0; g < 4; g++) {
            const float4* pw = (const float4*)(Whh + (size_t)(64*g + l) * H);
            #pragma unroll
            for (int k = 0; k < 16; k++) {
                float4 a = pw[k];
                h2 lo; lo.x = (_Float16)a.x; lo.y = (_Float16)a.y;
                h2 hi; hi.x = (_Float16)a.z; hi.y = (_Float16)a.w;
                wsh[g*32 + 2*k]   = lo;
                wsh[g*32 + 2*k+1] = hi;
            }
            bb[g] = bih[64*g + l] + bhh[64*g + l];
        }
        hln[grp][l] = (_Float16)0.0f;     // own-wave line, no barrier needed
    } else {
        const int pw = wl - 1;
        rA = pw * 128 + l; rB = pw * 128 + 64 + l;
        const float4* pa = (const float4*)(Wih + (size_t)rA * 128);
        const float4* pb = (const float4*)(Wih + (size_t)rB * 128);
        #pragma unroll
        for (int k = 0; k < 32; k++) {
            float4 a = pa[k], b2 = pb[k];
            h2 alo; alo.x = (_Float16)a.x;  alo.y = (_Float16)a.y;
            h2 ahi; ahi.x = (_Float16)a.z;  ahi.y = (_Float16)a.w;
            h2 blo; blo.x = (_Float16)b2.x; blo.y = (_Float16)b2.y;
            h2 bhi; bhi.x = (_Float16)b2.z; bhi.y = (_Float16)b2.w;
            wsh[2*k]        = alo;
            wsh[2*k + 1]    = ahi;
            wsh[64 + 2*k]   = blo;
            wsh[64 + 2*k+1] = bhi;
        }
    }

    uint4 st0;
    auto stage_load = [&](int ck) {
        const uint4* gp = (const uint4*)(hseq + (size_t)ck * CH * 128);
        st0 = gp[(wl - 1) * 64 + l];
    };
    auto stage_store = [&](int ck) {
        uint4* dp = (uint4*)&hst[grp][ck & 1][0][0];
        dp[(wl - 1) * 64 + l] = st0;
    };
    auto produce = [&](int ck) {
        const int par = ck & 1;
        for (int r = 0; r < CH; r++) {
            const uint4* rp = (const uint4*)&hst[grp][par][r][0];
            // 8 independent chains, round-robin (R8 change)
            float aA0=0.f, aA1=0.f, aA2=0.f, aA3=0.f;
            float aB0=0.f, aB1=0.f, aB2=0.f, aB3=0.f;
            #pragma unroll
            for (int q = 0; q < 16; q++) {
                uint4 u = rp[q];
                h2 p0 = u2h(u.x), p1 = u2h(u.y), p2 = u2h(u.z), p3 = u2h(u.w);
                aA0 = fdot2_(wsh[4*q+0],    p0, aA0);
                aB0 = fdot2_(wsh[64+4*q+0], p0, aB0);
                aA1 = fdot2_(wsh[4*q+1],    p1, aA1);
                aB1 = fdot2_(wsh[64+4*q+1], p1, aB1);
                aA2 = fdot2_(wsh[4*q+2],    p2, aA2);
                aB2 = fdot2_(wsh[64+4*q+2], p2, aB2);
                aA3 = fdot2_(wsh[4*q+3],    p3, aA3);
                aB3 = fdot2_(wsh[64+4*q+3], p3, aB3);
            }
            xw[grp][par][r][rA] = (aA0 + aA1) + (aA2 + aA3);
            xw[grp][par][r][rB] = (aB0 + aB1) + (aB2 + aB3);
        }
    };

    float c = 0.f, h = 0.f;

    if (wl >= 1) { stage_load(0); stage_store(0); if (nch > 1) stage_load(1); }
    __syncthreads();
    if (wl >= 1) { produce(0); if (nch > 1) stage_store(1); }
    __syncthreads();

    for (int cc = 0; cc < nchMax; cc++) {
        if (wl == 0) {
            const int sbeg = cc * CH;
            const int send = (sbeg + CH < L) ? (sbeg + CH) : L;
            const int par = cc & 1;
            for (int s = sbeg; s < send; s++) {
                const int r = s - sbeg;
                float p[4];
                #pragma unroll
                for (int g = 0; g < 4; g++)
                    p[g] = xw[grp][par][r][g*64 + l] + bb[g];
                // 16 independent dot2 chains, round-robin (R8 change)
                float ac0[4] = {0.f,0.f,0.f,0.f}, ac1[4] = {0.f,0.f,0.f,0.f};
                float ac2[4] = {0.f,0.f,0.f,0.f}, ac3[4] = {0.f,0.f,0.f,0.f};
                const uint4* h4 = (const uint4*)&hln[grp][0];
                #pragma unroll
                for (int q = 0; q < 8; q++) {
                    uint4 u = h4[q];
                    h2 p0 = u2h(u.x), p1 = u2h(u.y), p2 = u2h(u.z), p3 = u2h(u.w);
                    #pragma unroll
                    for (int g = 0; g < 4; g++) ac0[g] = fdot2_(wsh[g*32+4*q+0], p0, ac0[g]);
                    #pragma unroll
                    for (int g = 0; g < 4; g++) ac1[g] = fdot2_(wsh[g*32+4*q+1], p1, ac1[g]);
                    #pragma unroll
                    for (int g = 0; g < 4; g++) ac2[g] = fdot2_(wsh[g*32+4*q+2], p2, ac2[g]);
                    #pragma unroll
                    for (int g = 0; g < 4; g++) ac3[g] = fdot2_(wsh[g*32+4*q+3], p3, ac3[g]);
                }
                #pragma unroll
                for (int g = 0; g < 4; g++)
                    p[g] += (ac0[g] + ac1[g]) + (ac2[g] + ac3[g]);
                const float gi = sigmoidf_(p[0]);
                const float gf = sigmoidf_(p[1]);
                const float gg = tanhf_(p[2]);
                const float go = sigmoidf_(p[3]);
                c = fmaf(gf, c, gi * gg);
                h = go * tanhf_(c);
                hln[grp][l] = (_Float16)h;    // own-wave, no barrier
            }
        } else {
            if (cc + 2 < nch) stage_load(cc + 2);
            if (cc + 1 < nch) produce(cc + 1);
            if (cc + 2 < nch) stage_store(cc + 2);
        }
        __syncthreads();                  // ONE barrier per CH steps
    }

    // ---- epilogue: y = [h1f_last, h1b_first]; logits = y @ Wout^T + bout ---
    if (wl == 0) ybuf[grp][l] = h;
    if (tl < 128) h0r[grp][tl] = (float)hseq[(size_t)(L - 1) * 128 + tl];
    __syncthreads();
    {
        const int row = (tl < 64) ? tl : (tl + 64);
        const float4* wr = (const float4*)(WihB + (size_t)row * 128);
        const float4* xr = (const float4*)&h0r[grp][0];
        v2 a0 = mkv2(bihB[row] + bhhB[row], 0.f), a1 = mkv2(0.f, 0.f);
        #pragma unroll
        for (int k = 0; k < 32; k++) {
            float4 wv = wr[k], xv = xr[k];
            a0 += mkv2(wv.x, wv.y) * mkv2(xv.x, xv.y);
            a1 += mkv2(wv.z, wv.w) * mkv2(xv.z, xv.w);
        }
        const float a = (a0.x + a0.y) + (a1.x + a1.y);
        gb[grp][tl] = (tl >= 64 && tl < 128) ? tanhf_(a) : sigmoidf_(a);
    }
    __syncthreads();
    if (tl < 64) {
        // gb holds ACTIVATED gates: sigma(i), tanh(g), sigma(o) — combine raw
        const float hb = gb[grp][128 + tl] * tanhf_(gb[grp][tl] * gb[grp][64 + tl]);
        ybuf[grp][H + tl] = hb;
    }
    __syncthreads();
    const float4* yv = (const float4*)&ybuf[grp][0];
    for (int o = tl; o < NC; o += 192) {
        const float4* wr = (const float4*)(Wout + (size_t)o * 128);
        v2 a0 = mkv2(bout[o], 0.f), a1 = mkv2(0.f, 0.f);
        #pragma unroll
        for (int k = 0; k < 32; k++) {
            float4 wv = wr[k], yy = yv[k];
            a0 += mkv2(wv.x, wv.y) * mkv2(yy.x, yy.y);
            a1 += mkv2(wv.z, wv.w) * mkv2(yy.z, yy.w);
        }
        out[(size_t)seq * NC + o] = (a0.x + a0.y) + (a1.x + a1.y);
    }
}

extern "C" void kernel_launch(void* const* d_in, const int* in_sizes, int n_in,
                              void* d_out, int out_size, void* d_ws, size_t ws_size,
                              hipStream_t stream) {
    const float* x        = (const float*)d_in[0];
    const int*   lengths  = (const int*)  d_in[1];
    const float* Wih_l0f  = (const float*)d_in[2];
    const float* Whh_l0f  = (const float*)d_in[3];
    const float* bih_l0f  = (const float*)d_in[4];
    const float* bhh_l0f  = (const float*)d_in[5];
    const float* Wih_l0b  = (const float*)d_in[6];
    const float* Whh_l0b  = (const float*)d_in[7];
    const float* bih_l0b  = (const float*)d_in[8];
    const float* bhh_l0b  = (const float*)d_in[9];
    const float* Wih_l1f  = (const float*)d_in[10];
    const float* Whh_l1f  = (const float*)d_in[11];
    const float* bih_l1f  = (const float*)d_in[12];
    const float* bhh_l1f  = (const float*)d_in[13];
    const float* Wih_l1b  = (const float*)d_in[14];
    // d_in[15] = Whh_l1b: unused (backward dir only needs its first step, h=0)
    const float* bih_l1b  = (const float*)d_in[16];
    const float* bhh_l1b  = (const float*)d_in[17];
    const float* Wout     = (const float*)d_in[18];
    const float* bout     = (const float*)d_in[19];
    float* out = (float*)d_out;

    // ws: h0 f16 [B, T, 128] = 128 MiB
    _Float16* h0 = (_Float16*)d_ws;

    lstm_l0<<<dim3(BATCH / 2), 256, 0, stream>>>(
        x, lengths,
        Wih_l0f, Whh_l0f, bih_l0f, bhh_l0f,
        Wih_l0b, Whh_l0b, bih_l0b, bhh_l0b, h0);

    lstm_l1<<<dim3(BATCH / 2), 384, 0, stream>>>(
        h0, lengths,
        Wih_l1f, Whh_l1f, bih_l1f, bhh_l1f,
        Wih_l1b, bih_l1b, bhh_l1b, Wout, bout, out);
}